// Round 2
// baseline (396.473 us; speedup 1.0000x reference)
//
#include <hip/hip_runtime.h>
#include <hip/hip_bf16.h>

#define HH   512
#define BB   8192
#define WIDTH (1.0f/16.0f)

typedef __attribute__((ext_vector_type(8))) short  short8;   // 8 bf16 = 4 VGPRs
typedef __attribute__((ext_vector_type(4))) float  floatx4;

typedef const __attribute__((address_space(1))) void* gptr_t;
typedef __attribute__((address_space(3))) void*       lptr_t;

__device__ __forceinline__ void gload_lds16(const void* g, void* l) {
    // async global->LDS, 16B per lane; LDS dst = wave-uniform base + lane*16
    __builtin_amdgcn_global_load_lds((gptr_t)g, (lptr_t)l, 16, 0, 0);
}

__device__ __forceinline__ float tanh_fast(float x) {
    float e = __expf(2.0f * x);
    return 1.0f - 2.0f * __builtin_amdgcn_rcpf(e + 1.0f);
}

// ---------------- prep: c1[j] = b1[j] - 0.5 * sum_i W1[i][j] (fp32) ----------------
__global__ void prep_c1(const float* __restrict__ W1,
                        const float* __restrict__ b1,
                        float* __restrict__ c1) {
    int j = blockIdx.x * 256 + threadIdx.x;   // 512 columns
    float s = 0.0f;
    for (int i = 0; i < HH; ++i) s += W1[(size_t)i * HH + j];
    c1[j] = b1[j] - 0.5f * s;
}

// ------- convert passive half of v_in (fp32, row stride 1024) -> Abf (bf16, 8192x512) -------
__global__ void cvt_passive(const float* __restrict__ vin, __hip_bfloat16* __restrict__ Abf) {
    int i = blockIdx.x * 256 + threadIdx.x;    // 524288 groups of 8
    int b = i >> 6, c = i & 63;
    const float4* src = (const float4*)(vin + (size_t)b * 1024 + c * 8);
    float4 f0 = src[0], f1 = src[1];
    union { __hip_bfloat16 h[8]; uint4 v; } u;
    u.h[0] = __float2bfloat16(f0.x); u.h[1] = __float2bfloat16(f0.y);
    u.h[2] = __float2bfloat16(f0.z); u.h[3] = __float2bfloat16(f0.w);
    u.h[4] = __float2bfloat16(f1.x); u.h[5] = __float2bfloat16(f1.y);
    u.h[6] = __float2bfloat16(f1.z); u.h[7] = __float2bfloat16(f1.w);
    *(uint4*)(Abf + (size_t)b * 512 + c * 8) = u.v;
}

// ---------------- fp32 -> bf16 transpose: dst[c][r] = bf16(src[r][c]) ----------------
__global__ void transpose_f32_bf16(const float* __restrict__ src,
                                   __hip_bfloat16* __restrict__ dst,
                                   int rows, int cols) {
    __shared__ float tile[32][33];
    int c0 = blockIdx.x * 32, r0 = blockIdx.y * 32;
    int x = threadIdx.x, y = threadIdx.y;      // block (32,8)
    #pragma unroll
    for (int i = 0; i < 32; i += 8)
        tile[y + i][x] = src[(size_t)(r0 + y + i) * cols + c0 + x];
    __syncthreads();
    #pragma unroll
    for (int i = 0; i < 32; i += 8)
        dst[(size_t)(c0 + y + i) * rows + r0 + x] = __float2bfloat16(tile[x][y + i]);
}

// ---------------- passive copy: v_out[:, :512] = v_in[:, :512] (fp32) ----------------
__global__ void copy_passive(const float4* __restrict__ vin, float4* __restrict__ vout) {
    int i = blockIdx.x * 256 + threadIdx.x;    // 1048576 chunks of 4 floats
    int b = i >> 7, c = i & 127;               // 128 chunks = 512 passive floats
    vout[(size_t)b * 256 + c] = vin[(size_t)b * 256 + c];  // row = 256 chunks
}

// ---------------- GEMM1: h = tanh(Abf @ W1T^T + c1), output bf16 ----------------
__global__ __launch_bounds__(256, 2) void gemm1_kernel(
        const __hip_bfloat16* __restrict__ Abf,   // (8192,512) bf16
        const __hip_bfloat16* __restrict__ W1T,   // (512,512) [n][k] bf16
        const float* __restrict__ c1,
        __hip_bfloat16* __restrict__ hM) {        // (8192,512) bf16
    __shared__ short ldsA[128 * 32];
    __shared__ short ldsB[128 * 32];
    int tid = threadIdx.x;
    int lane = tid & 63;
    int wv = tid >> 6, wr = wv >> 1, wc = wv & 1;
    int q = lane >> 4, cx = lane & 15;
    int rowBase = blockIdx.y * 128;
    int colBase = blockIdx.x * 128;
    floatx4 acc[4][4] = {};

    for (int k0 = 0; k0 < HH; k0 += 32) {
        #pragma unroll
        for (int j = 0; j < 2; ++j) {
            int i = j * 256 + tid;             // chunk idx, lane-consecutive per wave
            int row = i >> 2, kc = i & 3;
            unsigned loff = __builtin_amdgcn_readfirstlane((unsigned)((j * 256 + (tid & 192)) * 16));
            gload_lds16(Abf + (size_t)(rowBase + row) * HH + k0 + kc * 8, (char*)ldsA + loff);
            gload_lds16(W1T + (size_t)(colBase + row) * HH + k0 + kc * 8, (char*)ldsB + loff);
        }
        __syncthreads();
        short8 a[4], b[4];
        #pragma unroll
        for (int mt = 0; mt < 4; ++mt)
            a[mt] = *(const short8*)(ldsA + (wr * 64 + mt * 16 + cx) * 32 + q * 8);
        #pragma unroll
        for (int nt = 0; nt < 4; ++nt)
            b[nt] = *(const short8*)(ldsB + (wc * 64 + nt * 16 + cx) * 32 + q * 8);
        #pragma unroll
        for (int mt = 0; mt < 4; ++mt)
            #pragma unroll
            for (int nt = 0; nt < 4; ++nt)
                acc[mt][nt] = __builtin_amdgcn_mfma_f32_16x16x32_bf16(a[mt], b[nt], acc[mt][nt], 0, 0, 0);
        __syncthreads();
    }

    float c1v[4];
    #pragma unroll
    for (int nt = 0; nt < 4; ++nt) c1v[nt] = c1[colBase + wc * 64 + nt * 16 + cx];
    #pragma unroll
    for (int mt = 0; mt < 4; ++mt)
        #pragma unroll
        for (int nt = 0; nt < 4; ++nt) {
            int col = colBase + wc * 64 + nt * 16 + cx;
            #pragma unroll
            for (int r = 0; r < 4; ++r) {
                int row = rowBase + wr * 64 + mt * 16 + q * 4 + r;  // C: col=lane&15, row=quad*4+reg
                hM[(size_t)row * HH + col] = __float2bfloat16(tanh_fast(acc[mt][nt][r] + c1v[nt]));
            }
        }
}

// ------- GEMM2 fused: net=tanh(h@W2+b2); softmax(16); spline; log-partials -------
__global__ __launch_bounds__(256, 2) void gemm2_kernel(
        const __hip_bfloat16* __restrict__ hM,    // (8192,512) bf16
        const __hip_bfloat16* __restrict__ W2T,   // (8192,512) [n][k] bf16
        const float* __restrict__ b2,             // (8192) fp32
        const float* __restrict__ vin,            // (8192,1024) fp32, active = cols 512..1023
        float* __restrict__ vout,                 // (8192,1024) fp32
        float* __restrict__ partial) {            // (8192,128) fp32
    __shared__ short ldsA[128 * 32];
    __shared__ short ldsB[128 * 32];
    int tid = threadIdx.x;
    int lane = tid & 63;
    int wv = tid >> 6, wr = wv >> 1, wc = wv & 1;
    int q = lane >> 4, cx = lane & 15;
    int rowBase = blockIdx.y * 128;
    int colBase = blockIdx.x * 128;
    floatx4 acc[4][4] = {};

    for (int k0 = 0; k0 < HH; k0 += 32) {
        #pragma unroll
        for (int j = 0; j < 2; ++j) {
            int i = j * 256 + tid;
            int row = i >> 2, kc = i & 3;
            unsigned loff = __builtin_amdgcn_readfirstlane((unsigned)((j * 256 + (tid & 192)) * 16));
            gload_lds16(hM  + (size_t)(rowBase + row) * HH + k0 + kc * 8, (char*)ldsA + loff);
            gload_lds16(W2T + (size_t)(colBase + row) * HH + k0 + kc * 8, (char*)ldsB + loff);
        }
        __syncthreads();
        short8 a[4], b[4];
        #pragma unroll
        for (int mt = 0; mt < 4; ++mt)
            a[mt] = *(const short8*)(ldsA + (wr * 64 + mt * 16 + cx) * 32 + q * 8);
        #pragma unroll
        for (int nt = 0; nt < 4; ++nt)
            b[nt] = *(const short8*)(ldsB + (wc * 64 + nt * 16 + cx) * 32 + q * 8);
        #pragma unroll
        for (int mt = 0; mt < 4; ++mt)
            #pragma unroll
            for (int nt = 0; nt < 4; ++nt)
                acc[mt][nt] = __builtin_amdgcn_mfma_f32_16x16x32_bf16(a[mt], b[nt], acc[mt][nt], 0, 0, 0);
        __syncthreads();
    }

    // Epilogue: each 16x16 C-tile = one softmax group per row (16 lanes = 16 bins)
    int colT = colBase + wc * 64;
    float b2v[4];
    #pragma unroll
    for (int nt = 0; nt < 4; ++nt) b2v[nt] = b2[colT + nt * 16 + cx];

    #pragma unroll
    for (int mt = 0; mt < 4; ++mt) {
        #pragma unroll
        for (int r = 0; r < 4; ++r) {
            int row = rowBase + wr * 64 + mt * 16 + q * 4 + r;
            float logacc = 0.0f;
            #pragma unroll
            for (int nt = 0; nt < 4; ++nt) {
                float t = tanh_fast(acc[mt][nt][r] + b2v[nt]);
                float e = __expf(t);              // t in [-1,1]: no max-subtract needed
                float s = e;
                s += __shfl_xor(s, 1, 16);
                s += __shfl_xor(s, 2, 16);
                s += __shfl_xor(s, 4, 16);
                s += __shfl_xor(s, 8, 16);
                float inc = e, tmp;               // inclusive scan over 16 lanes
                tmp = __shfl_up(inc, 1, 16); if (cx >= 1) inc += tmp;
                tmp = __shfl_up(inc, 2, 16); if (cx >= 2) inc += tmp;
                tmp = __shfl_up(inc, 4, 16); if (cx >= 4) inc += tmp;
                tmp = __shfl_up(inc, 8, 16); if (cx >= 8) inc += tmp;
                int g = (colT + nt * 16) >> 4;    // h-group index for this 16-col block
                float v = vin[(size_t)row * 1024 + 512 + g];
                int k = (int)ceilf(v * 16.0f) - 1;   // exact searchsorted('left')-1
                k = min(15, max(0, k));
                float ek = __shfl(e,   k, 16);
                float ik = __shfl(inc, k, 16);
                float rs = __builtin_amdgcn_rcpf(s);
                float pk  = ek * rs;
                float ylo = (ik - ek) * rs;          // cumsum below bin k
                float alpha = (v - (float)k * WIDTH) * 16.0f;
                float vo = ylo + alpha * pk;
                logacc += __logf(pk);
                if (cx == 0) vout[(size_t)row * 1024 + 512 + g] = vo;
            }
            if (cx == 0) partial[(size_t)row * 128 + blockIdx.x * 2 + wc] = logacc;
        }
    }
}

// ---------------- final: ld_out[b] = ld[b] - sum_{cb} partial[b][cb] ----------------
__global__ void finish_logdens(const float* __restrict__ partial,
                               const float* __restrict__ ld,
                               float* __restrict__ out) {
    int wv = threadIdx.x >> 6, lane = threadIdx.x & 63;
    int row = blockIdx.x * 4 + wv;
    float s = partial[(size_t)row * 128 + lane] + partial[(size_t)row * 128 + 64 + lane];
    #pragma unroll
    for (int d = 32; d > 0; d >>= 1) s += __shfl_down(s, d, 64);
    if (lane == 0) out[row] = ld[row] - s;
}

extern "C" void kernel_launch(void* const* d_in, const int* in_sizes, int n_in,
                              void* d_out, int out_size, void* d_ws, size_t ws_size,
                              hipStream_t stream) {
    const float* vin = (const float*)d_in[0];
    const float* ld  = (const float*)d_in[1];
    const float* W1  = (const float*)d_in[2];
    const float* b1  = (const float*)d_in[3];
    const float* W2  = (const float*)d_in[4];
    const float* b2  = (const float*)d_in[5];
    float* vout  = (float*)d_out;
    float* ldout = vout + (size_t)BB * 1024;

    char* ws = (char*)d_ws;                                    // layout (16B aligned):
    __hip_bfloat16* Abf = (__hip_bfloat16*)(ws);               //  8 MB  @ 0
    __hip_bfloat16* W1T = (__hip_bfloat16*)(ws + 8388608);     //  0.5MB @ 8388608
    __hip_bfloat16* W2T = (__hip_bfloat16*)(ws + 8912896);     //  8 MB  @ 8912896
    __hip_bfloat16* hM  = (__hip_bfloat16*)(ws + 17301504);    //  8 MB  @ 17301504
    float* c1      = (float*)(ws + 25690112);                  //  2 KB
    float* partial = (float*)(ws + 25692160);                  //  4 MB  (total ~28.5MB)

    prep_c1<<<2, 256, 0, stream>>>(W1, b1, c1);
    cvt_passive<<<2048, 256, 0, stream>>>(vin, Abf);
    transpose_f32_bf16<<<dim3(16, 16),  dim3(32, 8), 0, stream>>>(W1, W1T, 512, 512);
    transpose_f32_bf16<<<dim3(256, 16), dim3(32, 8), 0, stream>>>(W2, W2T, 512, 8192);
    gemm1_kernel<<<dim3(4, 64), 256, 0, stream>>>(Abf, W1T, c1, hM);
    copy_passive<<<4096, 256, 0, stream>>>((const float4*)vin, (float4*)vout);
    gemm2_kernel<<<dim3(64, 64), 256, 0, stream>>>(hM, W2T, b2, vin, vout, partial);
    finish_logdens<<<2048, 256, 0, stream>>>(partial, ld, ldout);
}

// Round 3
// 252.784 us; speedup vs baseline: 1.5684x; 1.5684x over previous
//
#include <hip/hip_runtime.h>
#include <hip/hip_bf16.h>

#define HH   512
#define BB   8192
#define WIDTH (1.0f/16.0f)

typedef __attribute__((ext_vector_type(8))) short  short8;   // 8 bf16 = 4 VGPRs
typedef __attribute__((ext_vector_type(4))) float  floatx4;

typedef const __attribute__((address_space(1))) void* gptr_t;
typedef __attribute__((address_space(3))) void*       lptr_t;

__device__ __forceinline__ void gload_lds16(const void* g, void* l) {
    // async global->LDS, 16B per lane; LDS dst = wave-uniform base + lane*16
    __builtin_amdgcn_global_load_lds((gptr_t)g, (lptr_t)l, 16, 0, 0);
}

__device__ __forceinline__ float tanh_fast(float x) {
    float e = __expf(2.0f * x);
    return 1.0f - 2.0f * __builtin_amdgcn_rcpf(e + 1.0f);
}

// ---------------- prep: c1[j] = b1[j] - 0.5 * sum_i W1[i][j] (fp32) ----------------
__global__ void prep_c1(const float* __restrict__ W1,
                        const float* __restrict__ b1,
                        float* __restrict__ c1) {
    int j = blockIdx.x * 256 + threadIdx.x;   // 512 columns
    float s = 0.0f;
    for (int i = 0; i < HH; ++i) s += W1[(size_t)i * HH + j];
    c1[j] = b1[j] - 0.5f * s;
}

// ---- fused: v_out[:, :512] = v_in[:, :512] (fp32)  AND  Abf = bf16(v_in[:, :512]) ----
__global__ void prep_v(const float* __restrict__ vin,
                       float* __restrict__ vout,
                       __hip_bfloat16* __restrict__ Abf) {
    int i = blockIdx.x * 256 + threadIdx.x;    // 524288 groups of 8 floats
    int b = i >> 6, c = i & 63;
    const float4* src = (const float4*)(vin + (size_t)b * 1024 + c * 8);
    float4 f0 = src[0], f1 = src[1];
    float4* dst = (float4*)(vout + (size_t)b * 1024 + c * 8);
    dst[0] = f0; dst[1] = f1;
    union { __hip_bfloat16 h[8]; uint4 v; } u;
    u.h[0] = __float2bfloat16(f0.x); u.h[1] = __float2bfloat16(f0.y);
    u.h[2] = __float2bfloat16(f0.z); u.h[3] = __float2bfloat16(f0.w);
    u.h[4] = __float2bfloat16(f1.x); u.h[5] = __float2bfloat16(f1.y);
    u.h[6] = __float2bfloat16(f1.z); u.h[7] = __float2bfloat16(f1.w);
    *(uint4*)(Abf + (size_t)b * 512 + c * 8) = u.v;
}

// ---------------- fp32 -> bf16 transpose: dst[c][r] = bf16(src[r][c]) ----------------
__global__ void transpose_f32_bf16(const float* __restrict__ src,
                                   __hip_bfloat16* __restrict__ dst,
                                   int rows, int cols) {
    __shared__ float tile[32][33];
    int c0 = blockIdx.x * 32, r0 = blockIdx.y * 32;
    int x = threadIdx.x, y = threadIdx.y;      // block (32,8)
    #pragma unroll
    for (int i = 0; i < 32; i += 8)
        tile[y + i][x] = src[(size_t)(r0 + y + i) * cols + c0 + x];
    __syncthreads();
    #pragma unroll
    for (int i = 0; i < 32; i += 8)
        dst[(size_t)(c0 + y + i) * rows + r0 + x] = __float2bfloat16(tile[x][y + i]);
}

// ---------------- GEMM1: h = tanh(Abf @ W1T^T + c1), output bf16 ----------------
__global__ __launch_bounds__(256, 2) void gemm1_kernel(
        const __hip_bfloat16* __restrict__ Abf,   // (8192,512) bf16
        const __hip_bfloat16* __restrict__ W1T,   // (512,512) [n][k] bf16
        const float* __restrict__ c1,
        __hip_bfloat16* __restrict__ hM) {        // (8192,512) bf16
    __shared__ short ldsA[128 * 32];
    __shared__ short ldsB[128 * 32];
    int tid = threadIdx.x;
    int lane = tid & 63;
    int wv = tid >> 6, wr = wv >> 1, wc = wv & 1;
    int q = lane >> 4, cx = lane & 15;
    int rowBase = blockIdx.y * 128;
    int colBase = blockIdx.x * 128;
    floatx4 acc[4][4] = {};

    for (int k0 = 0; k0 < HH; k0 += 32) {
        #pragma unroll
        for (int j = 0; j < 2; ++j) {
            int i = j * 256 + tid;
            int row = i >> 2, kc = i & 3;
            unsigned loff = __builtin_amdgcn_readfirstlane((unsigned)((j * 256 + (tid & 192)) * 16));
            gload_lds16(Abf + (size_t)(rowBase + row) * HH + k0 + kc * 8, (char*)ldsA + loff);
            gload_lds16(W1T + (size_t)(colBase + row) * HH + k0 + kc * 8, (char*)ldsB + loff);
        }
        __syncthreads();
        short8 a[4], b[4];
        #pragma unroll
        for (int mt = 0; mt < 4; ++mt)
            a[mt] = *(const short8*)(ldsA + (wr * 64 + mt * 16 + cx) * 32 + q * 8);
        #pragma unroll
        for (int nt = 0; nt < 4; ++nt)
            b[nt] = *(const short8*)(ldsB + (wc * 64 + nt * 16 + cx) * 32 + q * 8);
        #pragma unroll
        for (int mt = 0; mt < 4; ++mt)
            #pragma unroll
            for (int nt = 0; nt < 4; ++nt)
                acc[mt][nt] = __builtin_amdgcn_mfma_f32_16x16x32_bf16(a[mt], b[nt], acc[mt][nt], 0, 0, 0);
        __syncthreads();
    }

    float c1v[4];
    #pragma unroll
    for (int nt = 0; nt < 4; ++nt) c1v[nt] = c1[colBase + wc * 64 + nt * 16 + cx];
    #pragma unroll
    for (int mt = 0; mt < 4; ++mt)
        #pragma unroll
        for (int nt = 0; nt < 4; ++nt) {
            int col = colBase + wc * 64 + nt * 16 + cx;
            #pragma unroll
            for (int r = 0; r < 4; ++r) {
                int row = rowBase + wr * 64 + mt * 16 + q * 4 + r;  // C: col=lane&15, row=quad*4+reg
                hM[(size_t)row * HH + col] = __float2bfloat16(tanh_fast(acc[mt][nt][r] + c1v[nt]));
            }
        }
}

// ------- GEMM2 fused: net=tanh(h@W2+b2); softmax(16); spline; log-partials -------
// Epilogue: LDS round-trip transpose -> each lane owns one (row,group) softmax serially.
__global__ __launch_bounds__(256, 2) void gemm2_kernel(
        const __hip_bfloat16* __restrict__ hM,    // (8192,512) bf16
        const __hip_bfloat16* __restrict__ W2T,   // (8192,512) [n][k] bf16
        const float* __restrict__ b2,             // (8192) fp32
        const float* __restrict__ vin,            // (8192,1024) fp32, active cols 512..1023
        float* __restrict__ vout,                 // (8192,1024) fp32
        float* __restrict__ partial) {            // (8192,128) fp32
    __shared__ short ldsA[128 * 32];
    __shared__ short ldsB[128 * 32];
    __shared__ float ldsE[4 * 16 * 68];           // per-wave 16x68 fp32 tile (pad 68: conflict-free)
    int tid = threadIdx.x;
    int lane = tid & 63;
    int wv = tid >> 6, wr = wv >> 1, wc = wv & 1;
    int q = lane >> 4, cx = lane & 15;
    int rowBase = blockIdx.y * 128;
    int colBase = blockIdx.x * 128;
    floatx4 acc[4][4] = {};

    for (int k0 = 0; k0 < HH; k0 += 32) {
        #pragma unroll
        for (int j = 0; j < 2; ++j) {
            int i = j * 256 + tid;
            int row = i >> 2, kc = i & 3;
            unsigned loff = __builtin_amdgcn_readfirstlane((unsigned)((j * 256 + (tid & 192)) * 16));
            gload_lds16(hM  + (size_t)(rowBase + row) * HH + k0 + kc * 8, (char*)ldsA + loff);
            gload_lds16(W2T + (size_t)(colBase + row) * HH + k0 + kc * 8, (char*)ldsB + loff);
        }
        __syncthreads();
        short8 a[4], b[4];
        #pragma unroll
        for (int mt = 0; mt < 4; ++mt)
            a[mt] = *(const short8*)(ldsA + (wr * 64 + mt * 16 + cx) * 32 + q * 8);
        #pragma unroll
        for (int nt = 0; nt < 4; ++nt)
            b[nt] = *(const short8*)(ldsB + (wc * 64 + nt * 16 + cx) * 32 + q * 8);
        #pragma unroll
        for (int mt = 0; mt < 4; ++mt)
            #pragma unroll
            for (int nt = 0; nt < 4; ++nt)
                acc[mt][nt] = __builtin_amdgcn_mfma_f32_16x16x32_bf16(a[mt], b[nt], acc[mt][nt], 0, 0, 0);
        __syncthreads();
    }

    float b2v[4];
    #pragma unroll
    for (int nt = 0; nt < 4; ++nt) b2v[nt] = b2[colBase + wc * 64 + nt * 16 + cx];

    float* myTile = ldsE + wv * (16 * 68);        // wave-private: no barrier needed
    int rowL  = lane & 15;                         // read-phase: lane's row within 16-row slab
    int gL    = lane >> 4;                         // lane's group (0..3) within wave's 64 cols
    int gAbs  = blockIdx.x * 8 + wc * 4 + gL;     // absolute h-group index

    #pragma unroll
    for (int mt = 0; mt < 4; ++mt) {
        // write phase: C-layout slab (16 rows x 64 cols) -> LDS, +b2 folded in
        #pragma unroll
        for (int nt = 0; nt < 4; ++nt)
            #pragma unroll
            for (int r = 0; r < 4; ++r)
                myTile[(q * 4 + r) * 68 + nt * 16 + cx] = acc[mt][nt][r] + b2v[nt];
        // no __syncthreads: tile is wave-private; compiler inserts lgkmcnt wait

        // read phase: lane owns (row=rowL, group=gL): 16 contiguous floats
        floatx4 x0 = *(const floatx4*)(myTile + rowL * 68 + gL * 16);
        floatx4 x1 = *(const floatx4*)(myTile + rowL * 68 + gL * 16 + 4);
        floatx4 x2 = *(const floatx4*)(myTile + rowL * 68 + gL * 16 + 8);
        floatx4 x3 = *(const floatx4*)(myTile + rowL * 68 + gL * 16 + 12);
        float xs[16] = { x0[0],x0[1],x0[2],x0[3], x1[0],x1[1],x1[2],x1[3],
                         x2[0],x2[1],x2[2],x2[3], x3[0],x3[1],x3[2],x3[3] };

        int row = rowBase + wr * 64 + mt * 16 + rowL;
        float v = vin[(size_t)row * 1024 + 512 + gAbs];
        int k = (int)ceilf(v * 16.0f) - 1;        // exact searchsorted('left')-1 (v*16 exact)
        k = min(15, max(0, k));

        float s = 0.0f, csum = 0.0f, ek = 0.0f;
        #pragma unroll
        for (int j = 0; j < 16; ++j) {
            float e2 = __expf(2.0f * xs[j]);
            float t  = 1.0f - 2.0f * __builtin_amdgcn_rcpf(e2 + 1.0f);   // tanh
            float e  = __expf(t);                 // t in [-1,1]: no max-subtract needed
            csum += (j < k)  ? e : 0.0f;
            ek    = (j == k) ? e : ek;
            s += e;
        }
        float rs = __builtin_amdgcn_rcpf(s);
        float pk  = ek * rs;
        float ylo = csum * rs;
        float alpha = (v - (float)k * WIDTH) * 16.0f;
        vout[(size_t)row * 1024 + 512 + gAbs] = ylo + alpha * pk;

        float logp = __logf(pk);
        logp += __shfl_xor(logp, 16, 64);          // reduce over 4 groups sharing a row
        logp += __shfl_xor(logp, 32, 64);
        if (lane < 16) partial[(size_t)row * 128 + blockIdx.x * 2 + wc] = logp;
    }
}

// ---------------- final: ld_out[b] = ld[b] - sum_{cb} partial[b][cb] ----------------
__global__ void finish_logdens(const float* __restrict__ partial,
                               const float* __restrict__ ld,
                               float* __restrict__ out) {
    int wv = threadIdx.x >> 6, lane = threadIdx.x & 63;
    int row = blockIdx.x * 4 + wv;
    float s = partial[(size_t)row * 128 + lane] + partial[(size_t)row * 128 + 64 + lane];
    #pragma unroll
    for (int d = 32; d > 0; d >>= 1) s += __shfl_down(s, d, 64);
    if (lane == 0) out[row] = ld[row] - s;
}

extern "C" void kernel_launch(void* const* d_in, const int* in_sizes, int n_in,
                              void* d_out, int out_size, void* d_ws, size_t ws_size,
                              hipStream_t stream) {
    const float* vin = (const float*)d_in[0];
    const float* ld  = (const float*)d_in[1];
    const float* W1  = (const float*)d_in[2];
    const float* b1  = (const float*)d_in[3];
    const float* W2  = (const float*)d_in[4];
    const float* b2  = (const float*)d_in[5];
    float* vout  = (float*)d_out;
    float* ldout = vout + (size_t)BB * 1024;

    char* ws = (char*)d_ws;                                    // layout (16B aligned):
    __hip_bfloat16* Abf = (__hip_bfloat16*)(ws);               //  8 MB  @ 0
    __hip_bfloat16* W1T = (__hip_bfloat16*)(ws + 8388608);     //  0.5MB
    __hip_bfloat16* W2T = (__hip_bfloat16*)(ws + 8912896);     //  8 MB
    __hip_bfloat16* hM  = (__hip_bfloat16*)(ws + 17301504);    //  8 MB
    float* c1      = (float*)(ws + 25690112);                  //  2 KB
    float* partial = (float*)(ws + 25692160);                  //  4 MB  (total ~28.5MB)

    prep_c1<<<2, 256, 0, stream>>>(W1, b1, c1);
    transpose_f32_bf16<<<dim3(16, 16),  dim3(32, 8), 0, stream>>>(W1, W1T, 512, 512);
    transpose_f32_bf16<<<dim3(256, 16), dim3(32, 8), 0, stream>>>(W2, W2T, 512, 8192);
    prep_v<<<2048, 256, 0, stream>>>(vin, vout, Abf);
    gemm1_kernel<<<dim3(4, 64), 256, 0, stream>>>(Abf, W1T, c1, hM);
    gemm2_kernel<<<dim3(64, 64), 256, 0, stream>>>(hM, W2T, b2, vin, vout, partial);
    finish_logdens<<<2048, 256, 0, stream>>>(partial, ld, ldout);
}

// Round 4
// 221.627 us; speedup vs baseline: 1.7889x; 1.1406x over previous
//
#include <hip/hip_runtime.h>
#include <hip/hip_bf16.h>

#define HH   512
#define BB   8192
#define WIDTH (1.0f/16.0f)

typedef __attribute__((ext_vector_type(8))) short  short8;   // 8 bf16 = 4 VGPRs
typedef __attribute__((ext_vector_type(4))) float  floatx4;

typedef const __attribute__((address_space(1))) void* gptr_t;
typedef __attribute__((address_space(3))) void*       lptr_t;

__device__ __forceinline__ void gload_lds16(const void* g, void* l) {
    // async global->LDS, 16B per lane; LDS dst = wave-uniform base + lane*16
    __builtin_amdgcn_global_load_lds((gptr_t)g, (lptr_t)l, 16, 0, 0);
}

__device__ __forceinline__ float tanh_fast(float x) {
    float e = __expf(2.0f * x);
    return 1.0f - 2.0f * __builtin_amdgcn_rcpf(e + 1.0f);
}

// -- fused: v_out[:, :512] = v_in[:, :512] (fp32)  AND  Abf = bf16(v_in[:, :512] - 0.5) --
__global__ void prep_v(const float* __restrict__ vin,
                       float* __restrict__ vout,
                       __hip_bfloat16* __restrict__ Abf) {
    int i = blockIdx.x * 256 + threadIdx.x;    // 524288 groups of 8 floats
    int b = i >> 6, c = i & 63;
    const float4* src = (const float4*)(vin + (size_t)b * 1024 + c * 8);
    float4 f0 = src[0], f1 = src[1];
    float4* dst = (float4*)(vout + (size_t)b * 1024 + c * 8);
    dst[0] = f0; dst[1] = f1;
    union { __hip_bfloat16 h[8]; uint4 v; } u;
    u.h[0] = __float2bfloat16(f0.x - 0.5f); u.h[1] = __float2bfloat16(f0.y - 0.5f);
    u.h[2] = __float2bfloat16(f0.z - 0.5f); u.h[3] = __float2bfloat16(f0.w - 0.5f);
    u.h[4] = __float2bfloat16(f1.x - 0.5f); u.h[5] = __float2bfloat16(f1.y - 0.5f);
    u.h[6] = __float2bfloat16(f1.z - 0.5f); u.h[7] = __float2bfloat16(f1.w - 0.5f);
    *(uint4*)(Abf + (size_t)b * 512 + c * 8) = u.v;
}

// ---------------- fp32 -> bf16 transpose: dst[c][r] = bf16(src[r][c]) ----------------
__global__ void transpose_f32_bf16(const float* __restrict__ src,
                                   __hip_bfloat16* __restrict__ dst,
                                   int rows, int cols) {
    __shared__ float tile[32][33];
    int c0 = blockIdx.x * 32, r0 = blockIdx.y * 32;
    int x = threadIdx.x, y = threadIdx.y;      // block (32,8)
    #pragma unroll
    for (int i = 0; i < 32; i += 8)
        tile[y + i][x] = src[(size_t)(r0 + y + i) * cols + c0 + x];
    __syncthreads();
    #pragma unroll
    for (int i = 0; i < 32; i += 8)
        dst[(size_t)(c0 + y + i) * rows + r0 + x] = __float2bfloat16(tile[x][y + i]);
}

// ---------------- GEMM1: h = tanh(Abf @ W1T^T + b1), output bf16 ----------------
__global__ __launch_bounds__(256, 2) void gemm1_kernel(
        const __hip_bfloat16* __restrict__ Abf,   // (8192,512) bf16, = v_p - 0.5
        const __hip_bfloat16* __restrict__ W1T,   // (512,512) [n][k] bf16
        const float* __restrict__ b1,
        __hip_bfloat16* __restrict__ hM) {        // (8192,512) bf16
    __shared__ short ldsA[128 * 32];
    __shared__ short ldsB[128 * 32];
    int tid = threadIdx.x;
    int lane = tid & 63;
    int wv = tid >> 6, wr = wv >> 1, wc = wv & 1;
    int q = lane >> 4, cx = lane & 15;
    int rowBase = blockIdx.y * 128;
    int colBase = blockIdx.x * 128;
    floatx4 acc[4][4] = {};

    for (int k0 = 0; k0 < HH; k0 += 32) {
        #pragma unroll
        for (int j = 0; j < 2; ++j) {
            int i = j * 256 + tid;
            int row = i >> 2, kc = i & 3;
            unsigned loff = __builtin_amdgcn_readfirstlane((unsigned)((j * 256 + (tid & 192)) * 16));
            gload_lds16(Abf + (size_t)(rowBase + row) * HH + k0 + kc * 8, (char*)ldsA + loff);
            gload_lds16(W1T + (size_t)(colBase + row) * HH + k0 + kc * 8, (char*)ldsB + loff);
        }
        __syncthreads();
        short8 a[4], b[4];
        #pragma unroll
        for (int mt = 0; mt < 4; ++mt)
            a[mt] = *(const short8*)(ldsA + (wr * 64 + mt * 16 + cx) * 32 + q * 8);
        #pragma unroll
        for (int nt = 0; nt < 4; ++nt)
            b[nt] = *(const short8*)(ldsB + (wc * 64 + nt * 16 + cx) * 32 + q * 8);
        #pragma unroll
        for (int mt = 0; mt < 4; ++mt)
            #pragma unroll
            for (int nt = 0; nt < 4; ++nt)
                acc[mt][nt] = __builtin_amdgcn_mfma_f32_16x16x32_bf16(a[mt], b[nt], acc[mt][nt], 0, 0, 0);
        __syncthreads();
    }

    float b1v[4];
    #pragma unroll
    for (int nt = 0; nt < 4; ++nt) b1v[nt] = b1[colBase + wc * 64 + nt * 16 + cx];
    #pragma unroll
    for (int mt = 0; mt < 4; ++mt)
        #pragma unroll
        for (int nt = 0; nt < 4; ++nt) {
            int col = colBase + wc * 64 + nt * 16 + cx;
            #pragma unroll
            for (int r = 0; r < 4; ++r) {
                int row = rowBase + wr * 64 + mt * 16 + q * 4 + r;  // C: col=lane&15, row=quad*4+reg
                hM[(size_t)row * HH + col] = __float2bfloat16(tanh_fast(acc[mt][nt][r] + b1v[nt]));
            }
        }
}

// ------- GEMM2 fused: net=tanh(h@W2+b2); softmax(16); spline; log-partials -------
// Epilogue reuses the (dead) K-loop staging LDS; lane owns one (row,group) softmax.
__global__ __launch_bounds__(256, 4) void gemm2_kernel(
        const __hip_bfloat16* __restrict__ hM,    // (8192,512) bf16
        const __hip_bfloat16* __restrict__ W2T,   // (8192,512) [n][k] bf16
        const float* __restrict__ b2,             // (8192) fp32
        const float* __restrict__ vin,            // (8192,1024) fp32, active cols 512..1023
        float* __restrict__ vout,                 // (8192,1024) fp32
        float* __restrict__ partial) {            // (8192,128) fp32
    __shared__ __align__(16) char smem[17408];    // K-loop: ldsA(8K)+ldsB(8K); epilogue: 4x16x68 fp32
    short* ldsA = (short*)smem;
    short* ldsB = (short*)(smem + 8192);
    float* ldsE = (float*)smem;
    int tid = threadIdx.x;
    int lane = tid & 63;
    int wv = tid >> 6, wr = wv >> 1, wc = wv & 1;
    int q = lane >> 4, cx = lane & 15;
    int rowBase = blockIdx.y * 128;
    int colBase = blockIdx.x * 128;
    floatx4 acc[4][4] = {};

    for (int k0 = 0; k0 < HH; k0 += 32) {
        #pragma unroll
        for (int j = 0; j < 2; ++j) {
            int i = j * 256 + tid;
            int row = i >> 2, kc = i & 3;
            unsigned loff = __builtin_amdgcn_readfirstlane((unsigned)((j * 256 + (tid & 192)) * 16));
            gload_lds16(hM  + (size_t)(rowBase + row) * HH + k0 + kc * 8, (char*)ldsA + loff);
            gload_lds16(W2T + (size_t)(colBase + row) * HH + k0 + kc * 8, (char*)ldsB + loff);
        }
        __syncthreads();
        short8 a[4], b[4];
        #pragma unroll
        for (int mt = 0; mt < 4; ++mt)
            a[mt] = *(const short8*)(ldsA + (wr * 64 + mt * 16 + cx) * 32 + q * 8);
        #pragma unroll
        for (int nt = 0; nt < 4; ++nt)
            b[nt] = *(const short8*)(ldsB + (wc * 64 + nt * 16 + cx) * 32 + q * 8);
        #pragma unroll
        for (int mt = 0; mt < 4; ++mt)
            #pragma unroll
            for (int nt = 0; nt < 4; ++nt)
                acc[mt][nt] = __builtin_amdgcn_mfma_f32_16x16x32_bf16(a[mt], b[nt], acc[mt][nt], 0, 0, 0);
        __syncthreads();   // after this, staging LDS is dead -> epilogue may reuse it
    }

    float b2v[4];
    #pragma unroll
    for (int nt = 0; nt < 4; ++nt) b2v[nt] = b2[colBase + wc * 64 + nt * 16 + cx];

    float* myTile = ldsE + wv * (16 * 68);        // wave-private: no barrier needed
    int rowL  = lane & 15;                         // read-phase: lane's row within 16-row slab
    int gL    = lane >> 4;                         // lane's group (0..3) within wave's 64 cols
    int gAbs  = blockIdx.x * 8 + wc * 4 + gL;     // absolute h-group index

    #pragma unroll
    for (int mt = 0; mt < 4; ++mt) {
        // write phase: C-layout slab (16 rows x 64 cols) -> LDS, +b2 folded in
        #pragma unroll
        for (int nt = 0; nt < 4; ++nt)
            #pragma unroll
            for (int r = 0; r < 4; ++r)
                myTile[(q * 4 + r) * 68 + nt * 16 + cx] = acc[mt][nt][r] + b2v[nt];
        // no __syncthreads: tile is wave-private; compiler inserts lgkmcnt wait

        // read phase: lane owns (row=rowL, group=gL): 16 contiguous floats
        floatx4 x0 = *(const floatx4*)(myTile + rowL * 68 + gL * 16);
        floatx4 x1 = *(const floatx4*)(myTile + rowL * 68 + gL * 16 + 4);
        floatx4 x2 = *(const floatx4*)(myTile + rowL * 68 + gL * 16 + 8);
        floatx4 x3 = *(const floatx4*)(myTile + rowL * 68 + gL * 16 + 12);
        float xs[16] = { x0[0],x0[1],x0[2],x0[3], x1[0],x1[1],x1[2],x1[3],
                         x2[0],x2[1],x2[2],x2[3], x3[0],x3[1],x3[2],x3[3] };

        int row = rowBase + wr * 64 + mt * 16 + rowL;
        float v = vin[(size_t)row * 1024 + 512 + gAbs];
        int k = (int)ceilf(v * 16.0f) - 1;        // exact searchsorted('left')-1 (v*16 exact)
        k = min(15, max(0, k));

        float s = 0.0f, csum = 0.0f, ek = 0.0f;
        #pragma unroll
        for (int j = 0; j < 16; ++j) {
            float e2 = __expf(2.0f * xs[j]);
            float t  = 1.0f - 2.0f * __builtin_amdgcn_rcpf(e2 + 1.0f);   // tanh
            float e  = __expf(t);                 // t in [-1,1]: no max-subtract needed
            csum += (j < k)  ? e : 0.0f;
            ek    = (j == k) ? e : ek;
            s += e;
        }
        float rs = __builtin_amdgcn_rcpf(s);
        float pk  = ek * rs;
        float ylo = csum * rs;
        float alpha = (v - (float)k * WIDTH) * 16.0f;
        vout[(size_t)row * 1024 + 512 + gAbs] = ylo + alpha * pk;

        float logp = __logf(pk);
        logp += __shfl_xor(logp, 16, 64);          // reduce over 4 groups sharing a row
        logp += __shfl_xor(logp, 32, 64);
        if (lane < 16) partial[(size_t)row * 128 + blockIdx.x * 2 + wc] = logp;
    }
}

// ---------------- final: ld_out[b] = ld[b] - sum_{cb} partial[b][cb] ----------------
__global__ void finish_logdens(const float* __restrict__ partial,
                               const float* __restrict__ ld,
                               float* __restrict__ out) {
    int wv = threadIdx.x >> 6, lane = threadIdx.x & 63;
    int row = blockIdx.x * 4 + wv;
    float s = partial[(size_t)row * 128 + lane] + partial[(size_t)row * 128 + 64 + lane];
    #pragma unroll
    for (int d = 32; d > 0; d >>= 1) s += __shfl_down(s, d, 64);
    if (lane == 0) out[row] = ld[row] - s;
}

extern "C" void kernel_launch(void* const* d_in, const int* in_sizes, int n_in,
                              void* d_out, int out_size, void* d_ws, size_t ws_size,
                              hipStream_t stream) {
    const float* vin = (const float*)d_in[0];
    const float* ld  = (const float*)d_in[1];
    const float* W1  = (const float*)d_in[2];
    const float* b1  = (const float*)d_in[3];
    const float* W2  = (const float*)d_in[4];
    const float* b2  = (const float*)d_in[5];
    float* vout  = (float*)d_out;
    float* ldout = vout + (size_t)BB * 1024;

    char* ws = (char*)d_ws;                                    // layout (16B aligned):
    __hip_bfloat16* Abf = (__hip_bfloat16*)(ws);               //  8 MB  @ 0
    __hip_bfloat16* W1T = (__hip_bfloat16*)(ws + 8388608);     //  0.5MB
    __hip_bfloat16* W2T = (__hip_bfloat16*)(ws + 8912896);     //  8 MB
    __hip_bfloat16* hM  = (__hip_bfloat16*)(ws + 17301504);    //  8 MB
    float* partial = (float*)(ws + 25690112);                  //  4 MB  (total ~28.5MB)

    transpose_f32_bf16<<<dim3(16, 16),  dim3(32, 8), 0, stream>>>(W1, W1T, 512, 512);
    transpose_f32_bf16<<<dim3(256, 16), dim3(32, 8), 0, stream>>>(W2, W2T, 512, 8192);
    prep_v<<<2048, 256, 0, stream>>>(vin, vout, Abf);
    gemm1_kernel<<<dim3(4, 64), 256, 0, stream>>>(Abf, W1T, b1, hM);
    gemm2_kernel<<<dim3(64, 64), 256, 0, stream>>>(hM, W2T, b2, vin, vout, partial);
    finish_logdens<<<2048, 256, 0, stream>>>(partial, ld, ldout);
}

// Round 5
// 211.440 us; speedup vs baseline: 1.8751x; 1.0482x over previous
//
#include <hip/hip_runtime.h>
#include <hip/hip_bf16.h>

#define HH   512
#define BB   8192
#define WIDTH (1.0f/16.0f)

typedef __attribute__((ext_vector_type(8))) short  short8;   // 8 bf16 = 4 VGPRs
typedef __attribute__((ext_vector_type(4))) float  floatx4;

typedef const __attribute__((address_space(1))) void* gptr_t;
typedef __attribute__((address_space(3))) void*       lptr_t;

__device__ __forceinline__ void gload_lds16(const void* g, void* l) {
    // async global->LDS, 16B per lane; LDS dst = wave-uniform base + lane*16
    __builtin_amdgcn_global_load_lds((gptr_t)g, (lptr_t)l, 16, 0, 0);
}

__device__ __forceinline__ float tanh_fast(float x) {
    float e = __expf(2.0f * x);
    return 1.0f - 2.0f * __builtin_amdgcn_rcpf(e + 1.0f);
}

// -- fused: v_out[:, :512] = v_in[:, :512] (fp32)  AND  Abf = bf16(v_in[:, :512] - 0.5) --
__global__ void prep_v(const float* __restrict__ vin,
                       float* __restrict__ vout,
                       __hip_bfloat16* __restrict__ Abf) {
    int i = blockIdx.x * 256 + threadIdx.x;    // 524288 groups of 8 floats
    int b = i >> 6, c = i & 63;
    const float4* src = (const float4*)(vin + (size_t)b * 1024 + c * 8);
    float4 f0 = src[0], f1 = src[1];
    float4* dst = (float4*)(vout + (size_t)b * 1024 + c * 8);
    dst[0] = f0; dst[1] = f1;
    union { __hip_bfloat16 h[8]; uint4 v; } u;
    u.h[0] = __float2bfloat16(f0.x - 0.5f); u.h[1] = __float2bfloat16(f0.y - 0.5f);
    u.h[2] = __float2bfloat16(f0.z - 0.5f); u.h[3] = __float2bfloat16(f0.w - 0.5f);
    u.h[4] = __float2bfloat16(f1.x - 0.5f); u.h[5] = __float2bfloat16(f1.y - 0.5f);
    u.h[6] = __float2bfloat16(f1.z - 0.5f); u.h[7] = __float2bfloat16(f1.w - 0.5f);
    *(uint4*)(Abf + (size_t)b * 512 + c * 8) = u.v;
}

// ---------------- fp32 -> bf16 transpose: dst[c][r] = bf16(src[r][c]) ----------------
__global__ void transpose_f32_bf16(const float* __restrict__ src,
                                   __hip_bfloat16* __restrict__ dst,
                                   int rows, int cols) {
    __shared__ float tile[32][33];
    int c0 = blockIdx.x * 32, r0 = blockIdx.y * 32;
    int x = threadIdx.x, y = threadIdx.y;      // block (32,8)
    #pragma unroll
    for (int i = 0; i < 32; i += 8)
        tile[y + i][x] = src[(size_t)(r0 + y + i) * cols + c0 + x];
    __syncthreads();
    #pragma unroll
    for (int i = 0; i < 32; i += 8)
        dst[(size_t)(c0 + y + i) * rows + r0 + x] = __float2bfloat16(tile[x][y + i]);
}

// ------- GEMM1: h = tanh(Abf @ W1T^T + b1), 64x128 tiles, 512 blocks (2/CU) -------
__global__ __launch_bounds__(256, 4) void gemm1_kernel(
        const __hip_bfloat16* __restrict__ Abf,   // (8192,512) bf16, = v_p - 0.5
        const __hip_bfloat16* __restrict__ W1T,   // (512,512) [n][k] bf16
        const float* __restrict__ b1,
        __hip_bfloat16* __restrict__ hM) {        // (8192,512) bf16
    __shared__ short ldsA[64 * 32];               // 4 KB
    __shared__ short ldsB[128 * 32];              // 8 KB
    int tid = threadIdx.x;
    int lane = tid & 63;
    int wv = tid >> 6, wr = wv >> 1, wc = wv & 1;
    int q = lane >> 4, cx = lane & 15;
    int rowBase = blockIdx.y * 64;
    int colBase = blockIdx.x * 128;
    floatx4 acc[2][4] = {};

    for (int k0 = 0; k0 < HH; k0 += 32) {
        {   // A tile: 64 rows x 32 k = 256 chunks, 1 per thread
            int row = tid >> 2, kc = tid & 3;
            unsigned loff = __builtin_amdgcn_readfirstlane((unsigned)((tid & 192) * 16));
            gload_lds16(Abf + (size_t)(rowBase + row) * HH + k0 + kc * 8, (char*)ldsA + loff);
        }
        #pragma unroll
        for (int j = 0; j < 2; ++j) {   // B tile: 128 x 32 = 512 chunks
            int i = j * 256 + tid;
            int row = i >> 2, kc = i & 3;
            unsigned loff = __builtin_amdgcn_readfirstlane((unsigned)((j * 256 + (tid & 192)) * 16));
            gload_lds16(W1T + (size_t)(colBase + row) * HH + k0 + kc * 8, (char*)ldsB + loff);
        }
        __syncthreads();
        short8 a[2], b[4];
        #pragma unroll
        for (int mt = 0; mt < 2; ++mt)
            a[mt] = *(const short8*)(ldsA + (wr * 32 + mt * 16 + cx) * 32 + q * 8);
        #pragma unroll
        for (int nt = 0; nt < 4; ++nt)
            b[nt] = *(const short8*)(ldsB + (wc * 64 + nt * 16 + cx) * 32 + q * 8);
        #pragma unroll
        for (int mt = 0; mt < 2; ++mt)
            #pragma unroll
            for (int nt = 0; nt < 4; ++nt)
                acc[mt][nt] = __builtin_amdgcn_mfma_f32_16x16x32_bf16(a[mt], b[nt], acc[mt][nt], 0, 0, 0);
        __syncthreads();
    }

    float b1v[4];
    #pragma unroll
    for (int nt = 0; nt < 4; ++nt) b1v[nt] = b1[colBase + wc * 64 + nt * 16 + cx];
    #pragma unroll
    for (int mt = 0; mt < 2; ++mt)
        #pragma unroll
        for (int nt = 0; nt < 4; ++nt) {
            int col = colBase + wc * 64 + nt * 16 + cx;
            #pragma unroll
            for (int r = 0; r < 4; ++r) {
                int row = rowBase + wr * 32 + mt * 16 + q * 4 + r;  // C: col=lane&15, row=quad*4+reg
                hM[(size_t)row * HH + col] = __float2bfloat16(tanh_fast(acc[mt][nt][r] + b1v[nt]));
            }
        }
}

// ------- GEMM2 fused: net=tanh(h@W2+b2); softmax(16); spline; log-partials -------
// BK=64 as two stacked BK=32 half-tiles: one barrier pair per 64 k (16 -> 8 iters).
__global__ __launch_bounds__(256, 4) void gemm2_kernel(
        const __hip_bfloat16* __restrict__ hM,    // (8192,512) bf16
        const __hip_bfloat16* __restrict__ W2T,   // (8192,512) [n][k] bf16
        const float* __restrict__ b2,             // (8192) fp32
        const float* __restrict__ vin,            // (8192,1024) fp32, active cols 512..1023
        float* __restrict__ vout,                 // (8192,1024) fp32
        float* __restrict__ partial) {            // (8192,128) fp32
    __shared__ __align__(16) char smem[32768];    // A: 2x8K halves, B: 2x8K; epilogue reuses
    short* ldsA = (short*)smem;                   // [half*4096 + row*32 + k] shorts
    short* ldsB = (short*)(smem + 16384);
    float* ldsE = (float*)smem;                   // epilogue: 4 waves x 16x68 fp32 (17408 B)
    int tid = threadIdx.x;
    int lane = tid & 63;
    int wv = tid >> 6, wr = wv >> 1, wc = wv & 1;
    int q = lane >> 4, cx = lane & 15;
    int rowBase = blockIdx.y * 128;
    int colBase = blockIdx.x * 128;
    floatx4 acc[4][4] = {};

    for (int k0 = 0; k0 < HH; k0 += 64) {
        #pragma unroll
        for (int j = 0; j < 4; ++j) {             // 1024 chunks per matrix: two BK=32 tiles
            int chunk = j * 256 + tid;
            int half  = j >> 1;                   // chunk>>9
            int c2    = chunk & 511;
            int row = c2 >> 2, kc = c2 & 3;
            unsigned loff = __builtin_amdgcn_readfirstlane((unsigned)((j * 256 + (tid & 192)) * 16));
            gload_lds16(hM  + (size_t)(rowBase + row) * HH + k0 + half * 32 + kc * 8, (char*)ldsA + loff);
            gload_lds16(W2T + (size_t)(colBase + row) * HH + k0 + half * 32 + kc * 8, (char*)ldsB + loff);
        }
        __syncthreads();
        #pragma unroll
        for (int s = 0; s < 2; ++s) {             // sub-step: +8KB immediate offset, same banks
            const short* pA = ldsA + s * 4096;
            const short* pB = ldsB + s * 4096;
            short8 a[4], b[4];
            #pragma unroll
            for (int mt = 0; mt < 4; ++mt)
                a[mt] = *(const short8*)(pA + (wr * 64 + mt * 16 + cx) * 32 + q * 8);
            #pragma unroll
            for (int nt = 0; nt < 4; ++nt)
                b[nt] = *(const short8*)(pB + (wc * 64 + nt * 16 + cx) * 32 + q * 8);
            #pragma unroll
            for (int mt = 0; mt < 4; ++mt)
                #pragma unroll
                for (int nt = 0; nt < 4; ++nt)
                    acc[mt][nt] = __builtin_amdgcn_mfma_f32_16x16x32_bf16(a[mt], b[nt], acc[mt][nt], 0, 0, 0);
        }
        __syncthreads();   // staging LDS dead after last iter -> epilogue may reuse
    }

    float b2v[4];
    #pragma unroll
    for (int nt = 0; nt < 4; ++nt) b2v[nt] = b2[colBase + wc * 64 + nt * 16 + cx];

    float* myTile = ldsE + wv * (16 * 68);        // wave-private: no barrier needed
    int rowL  = lane & 15;                         // read-phase: lane's row within 16-row slab
    int gL    = lane >> 4;                         // lane's group (0..3) within wave's 64 cols
    int gAbs  = blockIdx.x * 8 + wc * 4 + gL;     // absolute h-group index

    #pragma unroll
    for (int mt = 0; mt < 4; ++mt) {
        // write phase: C-layout slab (16 rows x 64 cols) -> LDS, +b2 folded in
        #pragma unroll
        for (int nt = 0; nt < 4; ++nt)
            #pragma unroll
            for (int r = 0; r < 4; ++r)
                myTile[(q * 4 + r) * 68 + nt * 16 + cx] = acc[mt][nt][r] + b2v[nt];
        // no __syncthreads: tile is wave-private; compiler inserts lgkmcnt wait

        // read phase: lane owns (row=rowL, group=gL): 16 contiguous floats
        floatx4 x0 = *(const floatx4*)(myTile + rowL * 68 + gL * 16);
        floatx4 x1 = *(const floatx4*)(myTile + rowL * 68 + gL * 16 + 4);
        floatx4 x2 = *(const floatx4*)(myTile + rowL * 68 + gL * 16 + 8);
        floatx4 x3 = *(const floatx4*)(myTile + rowL * 68 + gL * 16 + 12);
        float xs[16] = { x0[0],x0[1],x0[2],x0[3], x1[0],x1[1],x1[2],x1[3],
                         x2[0],x2[1],x2[2],x2[3], x3[0],x3[1],x3[2],x3[3] };

        int row = rowBase + wr * 64 + mt * 16 + rowL;
        float v = vin[(size_t)row * 1024 + 512 + gAbs];
        int k = (int)ceilf(v * 16.0f) - 1;        // exact searchsorted('left')-1 (v*16 exact)
        k = min(15, max(0, k));

        float s = 0.0f, csum = 0.0f, ek = 0.0f;
        #pragma unroll
        for (int j = 0; j < 16; ++j) {
            float e2 = __expf(2.0f * xs[j]);
            float t  = 1.0f - 2.0f * __builtin_amdgcn_rcpf(e2 + 1.0f);   // tanh
            float e  = __expf(t);                 // t in [-1,1]: no max-subtract needed
            csum += (j < k)  ? e : 0.0f;
            ek    = (j == k) ? e : ek;
            s += e;
        }
        float rs = __builtin_amdgcn_rcpf(s);
        float pk  = ek * rs;
        float ylo = csum * rs;
        float alpha = (v - (float)k * WIDTH) * 16.0f;
        vout[(size_t)row * 1024 + 512 + gAbs] = ylo + alpha * pk;

        float logp = __logf(pk);
        logp += __shfl_xor(logp, 16, 64);          // reduce over 4 groups sharing a row
        logp += __shfl_xor(logp, 32, 64);
        if (lane < 16) partial[(size_t)row * 128 + blockIdx.x * 2 + wc] = logp;
    }
}

// ---------------- final: ld_out[b] = ld[b] - sum_{cb} partial[b][cb] ----------------
__global__ void finish_logdens(const float* __restrict__ partial,
                               const float* __restrict__ ld,
                               float* __restrict__ out) {
    int wv = threadIdx.x >> 6, lane = threadIdx.x & 63;
    int row = blockIdx.x * 4 + wv;
    float s = partial[(size_t)row * 128 + lane] + partial[(size_t)row * 128 + 64 + lane];
    #pragma unroll
    for (int d = 32; d > 0; d >>= 1) s += __shfl_down(s, d, 64);
    if (lane == 0) out[row] = ld[row] - s;
}

extern "C" void kernel_launch(void* const* d_in, const int* in_sizes, int n_in,
                              void* d_out, int out_size, void* d_ws, size_t ws_size,
                              hipStream_t stream) {
    const float* vin = (const float*)d_in[0];
    const float* ld  = (const float*)d_in[1];
    const float* W1  = (const float*)d_in[2];
    const float* b1  = (const float*)d_in[3];
    const float* W2  = (const float*)d_in[4];
    const float* b2  = (const float*)d_in[5];
    float* vout  = (float*)d_out;
    float* ldout = vout + (size_t)BB * 1024;

    char* ws = (char*)d_ws;                                    // layout (16B aligned):
    __hip_bfloat16* Abf = (__hip_bfloat16*)(ws);               //  8 MB  @ 0
    __hip_bfloat16* W1T = (__hip_bfloat16*)(ws + 8388608);     //  0.5MB
    __hip_bfloat16* W2T = (__hip_bfloat16*)(ws + 8912896);     //  8 MB
    __hip_bfloat16* hM  = (__hip_bfloat16*)(ws + 17301504);    //  8 MB
    float* partial = (float*)(ws + 25690112);                  //  4 MB  (total ~28.5MB)

    transpose_f32_bf16<<<dim3(16, 16),  dim3(32, 8), 0, stream>>>(W1, W1T, 512, 512);
    transpose_f32_bf16<<<dim3(256, 16), dim3(32, 8), 0, stream>>>(W2, W2T, 512, 8192);
    prep_v<<<2048, 256, 0, stream>>>(vin, vout, Abf);
    gemm1_kernel<<<dim3(4, 128), 256, 0, stream>>>(Abf, W1T, b1, hM);
    gemm2_kernel<<<dim3(64, 64), 256, 0, stream>>>(hM, W2T, b2, vin, vout, partial);
    finish_logdens<<<2048, 256, 0, stream>>>(partial, ld, ldout);
}

// Round 6
// 207.391 us; speedup vs baseline: 1.9117x; 1.0195x over previous
//
#include <hip/hip_runtime.h>
#include <hip/hip_bf16.h>

#define HH   512
#define BB   8192
#define WIDTH (1.0f/16.0f)

typedef __attribute__((ext_vector_type(8))) short  short8;   // 8 bf16 = 4 VGPRs
typedef __attribute__((ext_vector_type(4))) float  floatx4;

typedef const __attribute__((address_space(1))) void* gptr_t;
typedef __attribute__((address_space(3))) void*       lptr_t;

__device__ __forceinline__ void gload_lds16(const void* g, void* l) {
    // async global->LDS, 16B per lane; LDS dst = wave-uniform base + lane*16
    __builtin_amdgcn_global_load_lds((gptr_t)g, (lptr_t)l, 16, 0, 0);
}

__device__ __forceinline__ float tanh_fast(float x) {
    float e = __expf(2.0f * x);
    return 1.0f - 2.0f * __builtin_amdgcn_rcpf(e + 1.0f);
}

// ---- prep_all: W2 transpose | W1 transpose | prep_v + ldout init, one dispatch ----
__global__ void prep_all(const float* __restrict__ vin, const float* __restrict__ W1,
                         const float* __restrict__ W2, const float* __restrict__ ld,
                         float* __restrict__ vout, float* __restrict__ ldout,
                         __hip_bfloat16* __restrict__ Abf,
                         __hip_bfloat16* __restrict__ W1T,
                         __hip_bfloat16* __restrict__ W2T) {
    __shared__ float tile[32][33];
    int bid = blockIdx.x, tid = threadIdx.x;
    if (bid < 4352) {
        // transpose branch: W2 (512x8192) for bid<4096, else W1 (512x512)
        const float* src;  __hip_bfloat16* dst;  int cols, c0, r0;
        if (bid < 4096) { src = W2; dst = W2T; cols = 8192; c0 = (bid & 255) * 32; r0 = (bid >> 8) * 32; }
        else            { int b = bid - 4096; src = W1; dst = W1T; cols = 512; c0 = (b & 15) * 32; r0 = (b >> 4) * 32; }
        int x = tid & 31, y = tid >> 5;            // (32,8) logical
        #pragma unroll
        for (int i = 0; i < 32; i += 8)
            tile[y + i][x] = src[(size_t)(r0 + y + i) * cols + c0 + x];
        __syncthreads();
        #pragma unroll
        for (int i = 0; i < 32; i += 8)
            dst[(size_t)(c0 + y + i) * 512 + r0 + x] = __float2bfloat16(tile[x][y + i]);
    } else {
        // prep_v branch: v_out[:, :512] = v_in[:, :512]; Abf = bf16(v_p - 0.5); ldout = ld
        int b = bid - 4352;                        // 0..2047, 4 rows per block
        int i = b * 256 + tid;                     // group-of-8 index
        int r = i >> 6, c = i & 63;
        const float4* src = (const float4*)(vin + (size_t)r * 1024 + c * 8);
        float4 f0 = src[0], f1 = src[1];
        float4* dst = (float4*)(vout + (size_t)r * 1024 + c * 8);
        dst[0] = f0; dst[1] = f1;
        union { __hip_bfloat16 h[8]; uint4 v; } u;
        u.h[0] = __float2bfloat16(f0.x - 0.5f); u.h[1] = __float2bfloat16(f0.y - 0.5f);
        u.h[2] = __float2bfloat16(f0.z - 0.5f); u.h[3] = __float2bfloat16(f0.w - 0.5f);
        u.h[4] = __float2bfloat16(f1.x - 0.5f); u.h[5] = __float2bfloat16(f1.y - 0.5f);
        u.h[6] = __float2bfloat16(f1.z - 0.5f); u.h[7] = __float2bfloat16(f1.w - 0.5f);
        *(uint4*)(Abf + (size_t)r * 512 + c * 8) = u.v;
        if (tid < 4) { int row = b * 4 + tid; ldout[row] = ld[row]; }
    }
}

// ------- GEMM1: h = tanh(Abf @ W1T^T + b1), 64x128 tiles, 512 blocks (2/CU) -------
__global__ __launch_bounds__(256, 4) void gemm1_kernel(
        const __hip_bfloat16* __restrict__ Abf,   // (8192,512) bf16, = v_p - 0.5
        const __hip_bfloat16* __restrict__ W1T,   // (512,512) [n][k] bf16
        const float* __restrict__ b1,
        __hip_bfloat16* __restrict__ hM) {        // (8192,512) bf16
    __shared__ short ldsA[64 * 32];               // 4 KB
    __shared__ short ldsB[128 * 32];              // 8 KB
    int tid = threadIdx.x;
    int lane = tid & 63;
    int wv = tid >> 6, wr = wv >> 1, wc = wv & 1;
    int q = lane >> 4, cx = lane & 15;
    int rowBase = blockIdx.y * 64;
    int colBase = blockIdx.x * 128;
    floatx4 acc[2][4] = {};

    for (int k0 = 0; k0 < HH; k0 += 32) {
        {   // A tile: 64 rows x 32 k = 256 chunks, 1 per thread
            int row = tid >> 2, kc = tid & 3;
            unsigned loff = __builtin_amdgcn_readfirstlane((unsigned)((tid & 192) * 16));
            gload_lds16(Abf + (size_t)(rowBase + row) * HH + k0 + kc * 8, (char*)ldsA + loff);
        }
        #pragma unroll
        for (int j = 0; j < 2; ++j) {   // B tile: 128 x 32 = 512 chunks
            int i = j * 256 + tid;
            int row = i >> 2, kc = i & 3;
            unsigned loff = __builtin_amdgcn_readfirstlane((unsigned)((j * 256 + (tid & 192)) * 16));
            gload_lds16(W1T + (size_t)(colBase + row) * HH + k0 + kc * 8, (char*)ldsB + loff);
        }
        __syncthreads();
        short8 a[2], b[4];
        #pragma unroll
        for (int mt = 0; mt < 2; ++mt)
            a[mt] = *(const short8*)(ldsA + (wr * 32 + mt * 16 + cx) * 32 + q * 8);
        #pragma unroll
        for (int nt = 0; nt < 4; ++nt)
            b[nt] = *(const short8*)(ldsB + (wc * 64 + nt * 16 + cx) * 32 + q * 8);
        #pragma unroll
        for (int mt = 0; mt < 2; ++mt)
            #pragma unroll
            for (int nt = 0; nt < 4; ++nt)
                acc[mt][nt] = __builtin_amdgcn_mfma_f32_16x16x32_bf16(a[mt], b[nt], acc[mt][nt], 0, 0, 0);
        __syncthreads();
    }

    float b1v[4];
    #pragma unroll
    for (int nt = 0; nt < 4; ++nt) b1v[nt] = b1[colBase + wc * 64 + nt * 16 + cx];
    #pragma unroll
    for (int mt = 0; mt < 2; ++mt)
        #pragma unroll
        for (int nt = 0; nt < 4; ++nt) {
            int col = colBase + wc * 64 + nt * 16 + cx;
            #pragma unroll
            for (int r = 0; r < 4; ++r) {
                int row = rowBase + wr * 32 + mt * 16 + q * 4 + r;  // C: col=lane&15, row=quad*4+reg
                hM[(size_t)row * HH + col] = __float2bfloat16(tanh_fast(acc[mt][nt][r] + b1v[nt]));
            }
        }
}

// ------- GEMM2 fused: net=tanh(h@W2+b2); softmax(16); spline; atomic log-dens -------
// BK=64 (two stacked BK=32 tiles). XOR source-swizzle on staging: k-chunk c of row r
// lands at chunk slot c^(r&3) -> ds_read_b128 conflicts 8-way -> 4-way.
__global__ __launch_bounds__(256, 4) void gemm2_kernel(
        const __hip_bfloat16* __restrict__ hM,    // (8192,512) bf16
        const __hip_bfloat16* __restrict__ W2T,   // (8192,512) [n][k] bf16
        const float* __restrict__ b2,             // (8192) fp32
        const float* __restrict__ vin,            // (8192,1024) fp32, active cols 512..1023
        float* __restrict__ vout,                 // (8192,1024) fp32
        float* __restrict__ ldout) {              // (8192) fp32, pre-initialized to ld
    __shared__ __align__(16) char smem[32768];    // A: 16K (2 halves), B: 16K; epilogue reuses
    short* ldsA = (short*)smem;
    short* ldsB = (short*)(smem + 16384);
    float* ldsE = (float*)smem;                   // epilogue: 4 waves x 16x68 fp32 (17408 B)
    int tid = threadIdx.x;
    int lane = tid & 63;
    int wv = tid >> 6, wr = wv >> 1, wc = wv & 1;
    int q = lane >> 4, cx = lane & 15;
    int rowBase = blockIdx.y * 128;
    int colBase = blockIdx.x * 128;
    floatx4 acc[4][4] = {};

    int aoff = (q ^ (cx & 3)) * 8;                // swizzled chunk offset for fragment reads

    for (int k0 = 0; k0 < HH; k0 += 64) {
        #pragma unroll
        for (int j = 0; j < 4; ++j) {             // 1024 chunks per matrix: two BK=32 tiles
            int chunk = j * 256 + tid;
            int half  = j >> 1;
            int c2    = chunk & 511;
            int row = c2 >> 2, kc = c2 & 3;
            int kcs = kc ^ (row & 3);             // source-side swizzle (4-lane permutation)
            unsigned loff = __builtin_amdgcn_readfirstlane((unsigned)((j * 256 + (tid & 192)) * 16));
            gload_lds16(hM  + (size_t)(rowBase + row) * HH + k0 + half * 32 + kcs * 8, (char*)ldsA + loff);
            gload_lds16(W2T + (size_t)(colBase + row) * HH + k0 + half * 32 + kcs * 8, (char*)ldsB + loff);
        }
        __syncthreads();
        #pragma unroll
        for (int s = 0; s < 2; ++s) {             // sub-step: +8KB immediate offset
            const short* pA = ldsA + s * 4096;
            const short* pB = ldsB + s * 4096;
            short8 a[4], b[4];
            #pragma unroll
            for (int mt = 0; mt < 4; ++mt)
                a[mt] = *(const short8*)(pA + (wr * 64 + mt * 16 + cx) * 32 + aoff);
            #pragma unroll
            for (int nt = 0; nt < 4; ++nt)
                b[nt] = *(const short8*)(pB + (wc * 64 + nt * 16 + cx) * 32 + aoff);
            #pragma unroll
            for (int mt = 0; mt < 4; ++mt)
                #pragma unroll
                for (int nt = 0; nt < 4; ++nt)
                    acc[mt][nt] = __builtin_amdgcn_mfma_f32_16x16x32_bf16(a[mt], b[nt], acc[mt][nt], 0, 0, 0);
        }
        __syncthreads();   // staging LDS dead after last iter -> epilogue may reuse
    }

    float b2v[4];
    #pragma unroll
    for (int nt = 0; nt < 4; ++nt) b2v[nt] = b2[colBase + wc * 64 + nt * 16 + cx];

    float* myTile = ldsE + wv * (16 * 68);        // wave-private: no barrier needed
    int rowL  = lane & 15;                         // read-phase: lane's row within 16-row slab
    int gL    = lane >> 4;                         // lane's group (0..3) within wave's 64 cols
    int gAbs  = blockIdx.x * 8 + wc * 4 + gL;     // absolute h-group index

    #pragma unroll
    for (int mt = 0; mt < 4; ++mt) {
        // write phase: C-layout slab (16 rows x 64 cols) -> LDS, +b2 folded in
        #pragma unroll
        for (int nt = 0; nt < 4; ++nt)
            #pragma unroll
            for (int r = 0; r < 4; ++r)
                myTile[(q * 4 + r) * 68 + nt * 16 + cx] = acc[mt][nt][r] + b2v[nt];
        // no __syncthreads: tile is wave-private; compiler inserts lgkmcnt wait

        // read phase: lane owns (row=rowL, group=gL): 16 contiguous floats
        floatx4 x0 = *(const floatx4*)(myTile + rowL * 68 + gL * 16);
        floatx4 x1 = *(const floatx4*)(myTile + rowL * 68 + gL * 16 + 4);
        floatx4 x2 = *(const floatx4*)(myTile + rowL * 68 + gL * 16 + 8);
        floatx4 x3 = *(const floatx4*)(myTile + rowL * 68 + gL * 16 + 12);
        float xs[16] = { x0[0],x0[1],x0[2],x0[3], x1[0],x1[1],x1[2],x1[3],
                         x2[0],x2[1],x2[2],x2[3], x3[0],x3[1],x3[2],x3[3] };

        int row = rowBase + wr * 64 + mt * 16 + rowL;
        float v = vin[(size_t)row * 1024 + 512 + gAbs];
        int k = (int)ceilf(v * 16.0f) - 1;        // exact searchsorted('left')-1 (v*16 exact)
        k = min(15, max(0, k));

        float s = 0.0f, csum = 0.0f, ek = 0.0f;
        #pragma unroll
        for (int j = 0; j < 16; ++j) {
            float e2 = __expf(2.0f * xs[j]);
            float t  = 1.0f - 2.0f * __builtin_amdgcn_rcpf(e2 + 1.0f);   // tanh
            float e  = __expf(t);                 // t in [-1,1]: no max-subtract needed
            csum += (j < k)  ? e : 0.0f;
            ek    = (j == k) ? e : ek;
            s += e;
        }
        float rs = __builtin_amdgcn_rcpf(s);
        float pk  = ek * rs;
        float ylo = csum * rs;
        float alpha = (v - (float)k * WIDTH) * 16.0f;
        vout[(size_t)row * 1024 + 512 + gAbs] = ylo + alpha * pk;

        float logp = __logf(pk);
        logp += __shfl_xor(logp, 16, 64);          // reduce over 4 groups sharing a row
        logp += __shfl_xor(logp, 32, 64);
        if (lane < 16) atomicAdd(ldout + row, -logp);
    }
}

extern "C" void kernel_launch(void* const* d_in, const int* in_sizes, int n_in,
                              void* d_out, int out_size, void* d_ws, size_t ws_size,
                              hipStream_t stream) {
    const float* vin = (const float*)d_in[0];
    const float* ld  = (const float*)d_in[1];
    const float* W1  = (const float*)d_in[2];
    const float* b1  = (const float*)d_in[3];
    const float* W2  = (const float*)d_in[4];
    const float* b2  = (const float*)d_in[5];
    float* vout  = (float*)d_out;
    float* ldout = vout + (size_t)BB * 1024;

    char* ws = (char*)d_ws;                                    // layout (16B aligned):
    __hip_bfloat16* Abf = (__hip_bfloat16*)(ws);               //  8 MB  @ 0
    __hip_bfloat16* W1T = (__hip_bfloat16*)(ws + 8388608);     //  0.5MB
    __hip_bfloat16* W2T = (__hip_bfloat16*)(ws + 8912896);     //  8 MB
    __hip_bfloat16* hM  = (__hip_bfloat16*)(ws + 17301504);    //  8 MB  (total ~24.5MB)

    prep_all<<<6400, 256, 0, stream>>>(vin, W1, W2, ld, vout, ldout, Abf, W1T, W2T);
    gemm1_kernel<<<dim3(4, 128), 256, 0, stream>>>(Abf, W1T, b1, hM);
    gemm2_kernel<<<dim3(64, 64), 256, 0, stream>>>(hM, W2T, b2, vin, vout, ldout);
}